// Round 6
// baseline (258.870 us; speedup 1.0000x reference)
//
#include <hip/hip_runtime.h>

// GraphFilter on MI355X: out = (1/3 + (2/3)/rs_i) X + (2/3) dinv_i * (A @ (dinv .* X))
// A = thr(F F^T, 1e-10), diag 0; rs = rowsum(A)+1; dinv = rs^-1/2.
// R7-R12 history: i8 MFMA pipeline; K-loop restructure (R8) and epilogue
// arithmetic (R9-R11) both proven ~neutral; simgemm frozen at ~64 us.
// R12: outgemm tn=1 (S read once). R13: simgemm 256x256 tiles — 528 blocks
// instead of 2080. Theory: per-block fixed costs (prologue drain + serial
// epilogue chain) dominate simgemm; amortize 4x. rs partials split into
// rs_cmat[32][2][NR] + rs_rmat[32][4][NR] (memset-zeroed; diag writes
// col-sums only). Two-phase direct/mirror transpose in 64 KB smem.

#define NR 8192
#define DC 512
#define KZN 4

typedef unsigned short u16;
typedef signed char i8;
typedef float f32x4 __attribute__((ext_vector_type(4)));
typedef int i32x4 __attribute__((ext_vector_type(4)));
typedef u16 u16x4 __attribute__((ext_vector_type(4)));

// quant scales
#define QF_INV 453.5714285f      // 127/0.28  (|F| <= ~0.25)
#define DEQA   4.8608093e-6f     // (0.28/127)^2
#define QS_INV 254.0f            // 127/0.5   (S in [0,0.5))
#define QY_INV 211.6666666f      // 127/0.6   (|Yt| <= ~0.53)
#define DEQ    1.8600229e-5f     // (0.5/127)*(0.6/127)

__device__ __forceinline__ float bf2f(u16 u) {
  union { unsigned u; float f; } v; v.u = ((unsigned)u) << 16; return v.f;
}
__device__ __forceinline__ u16 f2bf(float f) {
  union { float f; unsigned u; } v; v.f = f;
  unsigned r = v.u + 0x7fffu + ((v.u >> 16) & 1u);
  return (u16)(r >> 16);
}

// async 16B global->LDS (wave-uniform LDS base + lane*16 semantics)
__device__ __forceinline__ void async16(const void* ga, void* la) {
  __builtin_amdgcn_global_load_lds(
      (const __attribute__((address_space(1))) unsigned int*)ga,
      (__attribute__((address_space(3))) unsigned int*)la, 16, 0, 0);
}

// ---- i8 staging, 128-byte rows (BK=128): ROWSx128 i8 tile, NT threads ----
// Phys 16B slot s (row r = s>>3, phys chunk c = s&7) holds global chunk
// kq = c ^ (r&7): XOR spreads fragment ds_read_b128s across bank groups.
template <int ROWS, int NT>
__device__ __forceinline__ void stage_i8_k128(const i8* __restrict__ g, int ld,
                                              int row0, int k0, i8* lds, int tid) {
  constexpr int PER = (ROWS * 8) / NT;
#pragma unroll
  for (int q = 0; q < PER; ++q) {
    int s = q * NT + tid;
    int r = s >> 3;
    int kq = (s & 7) ^ (r & 7);
    async16(g + (size_t)(row0 + r) * ld + (k0 + kq * 16), lds + s * 16);
  }
}
// fragment: row m, chunk c = kc*4 + quad (c in 0..7)
__device__ __forceinline__ i32x4 frag_i8_k128(const i8* lds, int m, int c) {
  int phys = c ^ (m & 7);
  return *(const i32x4*)(lds + m * 128 + phys * 16);
}

// ---------- kernel 1: row L2-normalize X -> F (i8) ----------
__global__ __launch_bounds__(256) void k_normalize(const float* __restrict__ X,
                                                   i8* __restrict__ F) {
  int row = blockIdx.x;
  int tid = threadIdx.x;
  const float* xr = X + (size_t)row * DC;
  float2 v = *(const float2*)(xr + 2 * tid);
  float s = v.x * v.x + v.y * v.y;
#pragma unroll
  for (int off = 32; off; off >>= 1) s += __shfl_down(s, off);
  __shared__ float wsum[4];
  if ((tid & 63) == 0) wsum[tid >> 6] = s;
  __syncthreads();
  float tot = wsum[0] + wsum[1] + wsum[2] + wsum[3];
  float scale = QF_INV / fmaxf(sqrtf(tot), 1e-12f);
  int q0 = (int)rintf(v.x * scale);
  int q1 = (int)rintf(v.y * scale);
  q0 = q0 > 127 ? 127 : (q0 < -127 ? -127 : q0);
  q1 = q1 > 127 ? 127 : (q1 < -127 ? -127 : q1);
  u16 pk = (u16)((q0 & 255) | ((q1 & 255) << 8));
  ((u16*)(F + (size_t)row * DC))[tid] = pk;
}

// ---------- kernel 2: symmetric S = thr(F F^T), diag 0, i8 in / i8 out ----------
// 256x256 tiles, ti<=tj triangle (528 blocks), 512 threads (8 waves 2x4).
// Per-wave output 128x64 (acc[8][4] i32x4). BK=128 -> 4 barrier pairs.
// rs: col-sums -> rs_cmat[ti][wm][gj], row-sums -> rs_rmat[tj][wn][gi]
// (plain stores, unique writer per slot; unwritten slots pre-zeroed by memset;
// diag tile writes col-sums only).
__global__ __launch_bounds__(512, 2) void k_simgemm(const i8* __restrict__ F,
                                                    i8* __restrict__ S,
                                                    float* __restrict__ rs_cmat,
                                                    float* __restrict__ rs_rmat) {
  __shared__ alignas(16) char smem[65536];
  i8* As = (i8*)smem;            // 256x128 i8 = 32 KB
  i8* Bs = (i8*)(smem + 32768);  // 256x128 i8 = 32 KB
  int tid = threadIdx.x, lane = tid & 63, wave = tid >> 6;
  // triangle decode over 32 tiles: block -> (ti <= tj)
  int b = blockIdx.x;
  int tj = (int)((sqrtf(8.f * b + 1.f) - 1.f) * 0.5f);
  while ((tj + 1) * (tj + 2) / 2 <= b) ++tj;
  while (tj * (tj + 1) / 2 > b) --tj;
  int ti = b - tj * (tj + 1) / 2;
  bool diag = (ti == tj);

  int wm = wave >> 2, wn = wave & 3;  // 2 x 4 wave grid
  int quad = lane >> 4, col = lane & 15;
  i32x4 zero = {0, 0, 0, 0};
  i32x4 acc[8][4];
#pragma unroll
  for (int a = 0; a < 8; ++a)
#pragma unroll
    for (int c = 0; c < 4; ++c) acc[a][c] = zero;

  for (int kt = 0; kt < DC; kt += 128) {  // 4 iterations
    __syncthreads();
    stage_i8_k128<256, 512>(F, DC, ti * 256, kt, As, tid);
    stage_i8_k128<256, 512>(F, DC, tj * 256, kt, Bs, tid);
    __syncthreads();
#pragma unroll
    for (int kc = 0; kc < 2; ++kc) {
      i32x4 af[8], bfr[4];
#pragma unroll
      for (int mi = 0; mi < 8; ++mi)
        af[mi] = frag_i8_k128(As, wm * 128 + mi * 16 + col, kc * 4 + quad);
#pragma unroll
      for (int ni = 0; ni < 4; ++ni)
        bfr[ni] = frag_i8_k128(Bs, wn * 64 + ni * 16 + col, kc * 4 + quad);
#pragma unroll
      for (int mi = 0; mi < 8; ++mi)
#pragma unroll
        for (int ni = 0; ni < 4; ++ni)
          acc[mi][ni] = __builtin_amdgcn_mfma_i32_16x16x64_i8(af[mi], bfr[ni], acc[mi][ni], 0, 0, 0);
    }
  }

  // threshold in place (max(acc,0) == thr(v,1e-10) exactly) + diag-zero;
  // exact column/row sums in i32 (max 256*127*127*512 ~ 2.1e9 < 2^31? No:
  // col-sum spans 128 rows per wave, row-sum 64 cols per wave -> max
  // 128*127*127*512 ~ 1.06e9, safe).
  int csI[4] = {0, 0, 0, 0};
  int rvI[32];
#pragma unroll
  for (int u = 0; u < 32; ++u) rvI[u] = 0;
#pragma unroll
  for (int mi = 0; mi < 8; ++mi) {
#pragma unroll
    for (int r = 0; r < 4; ++r) {
      int gi = ti * 256 + wm * 128 + mi * 16 + quad * 4 + r;
#pragma unroll
      for (int ni = 0; ni < 4; ++ni) {
        int gj = tj * 256 + wn * 64 + ni * 16 + col;
        int a = acc[mi][ni][r];
        a = a > 0 ? a : 0;
        if (diag && gi == gj) a = 0;
        acc[mi][ni][r] = a;
        csI[ni] += a;
        rvI[mi * 4 + r] += a;
      }
    }
  }
  // per-wave column sums (128 rows each) -> slot rs_cmat[ti][wm][gj]
#pragma unroll
  for (int ni = 0; ni < 4; ++ni) {
    int c = csI[ni];
    c += __shfl_xor(c, 16);
    c += __shfl_xor(c, 32);
    if (quad == 0) {
      int gj = tj * 256 + wn * 64 + ni * 16 + col;
      rs_cmat[((size_t)ti * 2 + wm) * NR + gj] = (float)c * DEQA;
    }
  }
  // per-wave row sums (64 cols each) -> slot rs_rmat[tj][wn][gi] (non-diag)
  if (!diag) {
#pragma unroll
    for (int u = 0; u < 32; ++u) {
      int c = rvI[u];
      c += __shfl_xor(c, 1);
      c += __shfl_xor(c, 2);
      c += __shfl_xor(c, 4);
      c += __shfl_xor(c, 8);
      if (col == 0) {
        int mi = u >> 2, r = u & 3;
        int gi = ti * 256 + wm * 128 + mi * 16 + quad * 4 + r;
        rs_rmat[((size_t)tj * 4 + wn) * NR + gi] = (float)c * DEQA;
      }
    }
  }

  // ---- phase A: quantize + direct-layout transpose buffer (all 64 KB) ----
  char* buf = smem;  // 256x256 i8 = 64 KB
  __syncthreads();
#pragma unroll
  for (int mi = 0; mi < 8; ++mi) {
#pragma unroll
    for (int ni = 0; ni < 4; ++ni) {
      int cg = wn * 64 + ni * 16 + col;
#pragma unroll
      for (int r = 0; r < 4; ++r) {
        int a = acc[mi][ni][r];
        int qq = (int)rintf((float)a * (DEQA * QS_INV));
        qq = qq > 127 ? 127 : qq;
        int row = wm * 128 + mi * 16 + quad * 4 + r;
        int chunk = (cg >> 4) ^ (row & 15);
        buf[row * 256 + chunk * 16 + (cg & 15)] = (char)qq;
      }
    }
  }
  __syncthreads();
  // coalesced 16B global stores of direct tile
  {
    int r2 = tid >> 1, half = tid & 1;
#pragma unroll
    for (int k = 0; k < 8; ++k) {
      int c = half * 8 + k;
      int phys = c ^ (r2 & 15);
      i32x4 d = *(const i32x4*)(buf + r2 * 256 + phys * 16);
      *(i32x4*)(S + (size_t)(ti * 256 + r2) * NR + tj * 256 + c * 16) = d;
    }
  }
  // ---- phase B: mirror tile (transpose) ----
  if (!diag) {
    __syncthreads();
#pragma unroll
    for (int mi = 0; mi < 8; ++mi) {
#pragma unroll
      for (int ni = 0; ni < 4; ++ni) {
        int cg = wn * 64 + ni * 16 + col;
        int q[4];
#pragma unroll
        for (int r = 0; r < 4; ++r) {
          int a = acc[mi][ni][r];
          int qq = (int)rintf((float)a * (DEQA * QS_INV));
          q[r] = qq > 127 ? 127 : qq;
        }
        int mcb = wm * 128 + mi * 16 + quad * 4;
        int chunk = (mcb >> 4) ^ (cg & 15);
        unsigned pk = (unsigned)(q[0] & 255) | ((unsigned)(q[1] & 255) << 8) |
                      ((unsigned)(q[2] & 255) << 16) | ((unsigned)(q[3] & 255) << 24);
        *(unsigned*)(buf + cg * 256 + chunk * 16 + (mcb & 15)) = pk;
      }
    }
    __syncthreads();
    {
      int r2 = tid >> 1, half = tid & 1;
#pragma unroll
      for (int k = 0; k < 8; ++k) {
        int c = half * 8 + k;
        int phys = c ^ (r2 & 15);
        i32x4 d = *(const i32x4*)(buf + r2 * 256 + phys * 16);
        *(i32x4*)(S + (size_t)(tj * 256 + r2) * NR + ti * 256 + c * 16) = d;
      }
    }
  }
}

// ---------- kernel 2b: rsum1[i] = 1 + sum of 64 cmat + 128 rmat partials ----------
__global__ __launch_bounds__(128) void k_rs(const float* __restrict__ rs_cmat,
                                            const float* __restrict__ rs_rmat,
                                            float* __restrict__ rsum1) {
  int i = blockIdx.x * 128 + threadIdx.x;
  float s = 1.0f;
#pragma unroll
  for (int k = 0; k < 64; ++k) s += rs_cmat[(size_t)k * NR + i];
#pragma unroll
  for (int k = 0; k < 128; ++k) s += rs_rmat[(size_t)k * NR + i];
  rsum1[i] = s;
}

// ---------- kernel 3: Yt[n][j] = i8(dinv_j * X[j][n] / sY); dinv from rsum1 ----------
__global__ __launch_bounds__(256) void k_make_yt(const float* __restrict__ X,
                                                 const float* __restrict__ rsum1,
                                                 i8* __restrict__ Yt) {
  __shared__ float T[64][65];
  int i0 = blockIdx.x * 64, k0 = blockIdx.y * 64;
  int tid = threadIdx.x;
  {
    int iL = tid >> 2, ks = (tid & 3) * 4;
    const float* xr = X + (size_t)(i0 + iL) * DC + k0;
#pragma unroll
    for (int u = 0; u < 4; ++u) {
      float4 f = *(const float4*)(xr + ks + u * 16);
      T[iL][ks + u * 16 + 0] = f.x;
      T[iL][ks + u * 16 + 1] = f.y;
      T[iL][ks + u * 16 + 2] = f.z;
      T[iL][ks + u * 16 + 3] = f.w;
    }
  }
  __syncthreads();
  {
    int kL = tid >> 2, ib = (tid & 3) * 16;
    char pk[16];
#pragma unroll
    for (int u = 0; u < 16; ++u) {
      float dj = rsqrtf(rsum1[i0 + ib + u]);
      float v = T[ib + u][kL] * dj;
      int q = (int)rintf(v * QY_INV);
      q = q > 127 ? 127 : (q < -127 ? -127 : q);
      pk[u] = (char)q;
    }
    *(i32x4*)(Yt + (size_t)(k0 + kL) * NR + i0 + ib) = *(const i32x4*)pk;
  }
}

// ---------- kernel 4: split-K i8 GEMM partials = S @ Yt^T ----------
// tn=1 — block tile 128 rows x ALL 512 cols; S fetched from HBM once.
// 512 threads, 8 waves as 2(row)x4(col): per-wave 64x128 out (acc 4x8).
// LDS: As 16 KB + Ys 64 KB = 80 KB, grid (64, KZN).
__global__ __launch_bounds__(512, 2) void k_outgemm(const i8* __restrict__ S,
                                                    const i8* __restrict__ Yt,
                                                    u16* __restrict__ Pb) {
  __shared__ alignas(16) i8 As[128 * 128];  // 16 KB
  __shared__ alignas(16) i8 Ys[512 * 128];  // 64 KB
  int tid = threadIdx.x, lane = tid & 63, wave = tid >> 6;
  int ti = blockIdx.x, kz = blockIdx.y;
  int wm = wave & 1, wn = wave >> 1;  // 2 x 4 wave grid
  int quad = lane >> 4, col = lane & 15;
  i32x4 zero = {0, 0, 0, 0};
  i32x4 acc[4][8];
#pragma unroll
  for (int a = 0; a < 4; ++a)
#pragma unroll
    for (int c = 0; c < 8; ++c) acc[a][c] = zero;

  const int KCH = NR / KZN;
  int k_lo = kz * KCH, k_hi = k_lo + KCH;
  for (int kt = k_lo; kt < k_hi; kt += 128) {  // 16 iterations
    __syncthreads();
    stage_i8_k128<128, 512>(S, NR, ti * 128, kt, As, tid);
    stage_i8_k128<512, 512>(Yt, NR, 0, kt, Ys, tid);
    __syncthreads();
#pragma unroll
    for (int kc = 0; kc < 2; ++kc) {
      i32x4 af[4], bfr[8];
#pragma unroll
      for (int mi = 0; mi < 4; ++mi)
        af[mi] = frag_i8_k128(As, wm * 64 + mi * 16 + col, kc * 4 + quad);
#pragma unroll
      for (int ni = 0; ni < 8; ++ni)
        bfr[ni] = frag_i8_k128(Ys, wn * 128 + ni * 16 + col, kc * 4 + quad);
#pragma unroll
      for (int mi = 0; mi < 4; ++mi)
#pragma unroll
        for (int ni = 0; ni < 8; ++ni)
          acc[mi][ni] = __builtin_amdgcn_mfma_i32_16x16x64_i8(af[mi], bfr[ni], acc[mi][ni], 0, 0, 0);
    }
  }
#pragma unroll
  for (int mi = 0; mi < 4; ++mi) {
#pragma unroll
    for (int r = 0; r < 4; ++r) {
      int gi = ti * 128 + wm * 64 + mi * 16 + quad * 4 + r;
#pragma unroll
      for (int ni = 0; ni < 8; ++ni) {
        int gj = wn * 128 + ni * 16 + col;
        Pb[((size_t)kz * NR + gi) * DC + gj] = f2bf((float)acc[mi][ni][r] * DEQ);
      }
    }
  }
}

// ---------- kernel 5: reduce partials + xs*X -> out ----------
__global__ __launch_bounds__(256) void k_reduce(const u16* __restrict__ Pb,
                                               const float* __restrict__ X,
                                               const float* __restrict__ rsum1,
                                               float* __restrict__ out) {
  const float c1 = (float)(2.0 / 3.0);
  const float c0 = 1.0f - c1;
  size_t idx = ((size_t)blockIdx.x * 256 + threadIdx.x) * 4;
  int i = (int)(idx >> 9);  // row = idx / DC
  float4 s = {0.f, 0.f, 0.f, 0.f};
#pragma unroll
  for (int kz = 0; kz < KZN; ++kz) {
    u16x4 p = *(const u16x4*)(Pb + (size_t)kz * NR * DC + idx);
    s.x += bf2f(p[0]); s.y += bf2f(p[1]); s.z += bf2f(p[2]); s.w += bf2f(p[3]);
  }
  float4 x = *(const float4*)(X + idx);
  float rs = rsum1[i];
  float sc = c1 * rsqrtf(rs);
  float xs = c0 + c1 / rs;
  float4 o = {xs * x.x + sc * s.x, xs * x.y + sc * s.y,
              xs * x.z + sc * s.z, xs * x.w + sc * s.w};
  *(float4*)(out + idx) = o;
}

extern "C" void kernel_launch(void* const* d_in, const int* in_sizes, int n_in,
                              void* d_out, int out_size, void* d_ws, size_t ws_size,
                              hipStream_t stream) {
  const float* X = (const float*)d_in[0];
  float* out = (float*)d_out;
  char* ws = (char*)d_ws;
  // ws layout — total 109,084,672 B, byte-identical footprint to proven R7.
  // rs_cmat (2 MB) + rs_rmat (4 MB) ALIAS the start of Pb: fully consumed by
  // k_rs before k_outgemm writes Pb (same stream -> serialized).
  i8*  S  = (i8*)(ws);                         // 67108864
  i8*  F  = (i8*)(ws + 67108864);              //  4194304
  i8*  Yt = (i8*)(ws + 71303168);              //  4194304
  float* rsum1  = (float*)(ws + 75497472);     //    32768
  u16* Pb = (u16*)(ws + 75530240);             // KZN*8192*512*2 = 33554432
  float* rs_cmat = (float*)(ws + 75530240);            // 64*8192*4  = 2 MB (alias)
  float* rs_rmat = (float*)(ws + 75530240 + 2097152);  // 128*8192*4 = 4 MB (alias)

  k_normalize<<<dim3(NR), dim3(256), 0, stream>>>(X, F);
  hipMemsetAsync(ws + 75530240, 0, 6291456, stream);  // zero rs partials
  k_simgemm<<<dim3(32 * 33 / 2), dim3(512), 0, stream>>>(F, S, rs_cmat, rs_rmat);
  k_rs<<<dim3(64), dim3(128), 0, stream>>>(rs_cmat, rs_rmat, rsum1);
  k_make_yt<<<dim3(128, 8), dim3(256), 0, stream>>>(X, rsum1, Yt);
  k_outgemm<<<dim3(64, KZN), dim3(512), 0, stream>>>(S, Yt, Pb);
  k_reduce<<<dim3(NR * DC / 1024), dim3(256), 0, stream>>>(Pb, X, rsum1, out);
}

// Round 7
// 201.779 us; speedup vs baseline: 1.2829x; 1.2829x over previous
//
#include <hip/hip_runtime.h>

// GraphFilter on MI355X: out = (1/3 + (2/3)/rs_i) X + (2/3) dinv_i * (A @ (dinv .* X))
// A = thr(F F^T, 1e-10), diag 0; rs = rowsum(A)+1; dinv = rs^-1/2.
// History: R8 K-loop dbuf neutral; R9-R11 epilogue arithmetic neutral;
// R13 256^2 tiles REGRESSED (occupancy 31->17%, dur 64->98 ~ inverse-
// proportional). Diagnosis: simgemm is latency-bound, scales with resident
// waves. R14: raise occupancy ceiling — BK=64 staging (As+Bs=16KB) and
// two-phase 16KB epilogue transpose -> total LDS 16KB (was 32KB): LDS
// ceiling 5->10 blocks/CU (threads cap 8). Outgemm reverted to proven R7
// form (S re-read is L3-absorbed; R12 premise invalid).

#define NR 8192
#define DC 512
#define KZN 4

typedef unsigned short u16;
typedef signed char i8;
typedef float f32x4 __attribute__((ext_vector_type(4)));
typedef int i32x4 __attribute__((ext_vector_type(4)));
typedef u16 u16x4 __attribute__((ext_vector_type(4)));

// quant scales
#define QF_INV 453.5714285f      // 127/0.28  (|F| <= ~0.25)
#define DEQA   4.8608093e-6f     // (0.28/127)^2
#define QS_INV 254.0f            // 127/0.5   (S in [0,0.5))
#define QY_INV 211.6666666f      // 127/0.6   (|Yt| <= ~0.53)
#define DEQ    1.8600229e-5f     // (0.5/127)*(0.6/127)

__device__ __forceinline__ float bf2f(u16 u) {
  union { unsigned u; float f; } v; v.u = ((unsigned)u) << 16; return v.f;
}
__device__ __forceinline__ u16 f2bf(float f) {
  union { float f; unsigned u; } v; v.f = f;
  unsigned r = v.u + 0x7fffu + ((v.u >> 16) & 1u);
  return (u16)(r >> 16);
}

// async 16B global->LDS (wave-uniform LDS base + lane*16 semantics)
__device__ __forceinline__ void async16(const void* ga, void* la) {
  __builtin_amdgcn_global_load_lds(
      (const __attribute__((address_space(1))) unsigned int*)ga,
      (__attribute__((address_space(3))) unsigned int*)la, 16, 0, 0);
}

// ---- i8 staging, BK=128 (128-byte rows), used by outgemm ----
template <int ROWS, int NT>
__device__ __forceinline__ void stage_i8_k128(const i8* __restrict__ g, int ld,
                                              int row0, int k0, i8* lds, int tid) {
  constexpr int PER = (ROWS * 8) / NT;
#pragma unroll
  for (int q = 0; q < PER; ++q) {
    int s = q * NT + tid;
    int r = s >> 3;
    int kq = (s & 7) ^ (r & 7);
    async16(g + (size_t)(row0 + r) * ld + (k0 + kq * 16), lds + s * 16);
  }
}
// fragment: row m, chunk c = kc*4 + quad (c in 0..7)
__device__ __forceinline__ i32x4 frag_i8_k128(const i8* lds, int m, int c) {
  int phys = c ^ (m & 7);
  return *(const i32x4*)(lds + m * 128 + phys * 16);
}

// ---- i8 staging, BK=64 (64-byte rows), used by simgemm ----
// Write: slot s (r = s>>2, c = s&3) holds global chunk kq = c ^ ((r>>1)&3).
// Read: row m, K-chunk q at phys = q ^ ((m>>1)&3). Bank math: addr/4 =
// 16m + 4*phys; even/odd rows split bank halves, (m>>1)&3 cycles the 4
// chunk groups -> 2-way aliasing (free) for 16-col fragment reads.
template <int ROWS, int NT>
__device__ __forceinline__ void stage_i8_k64(const i8* __restrict__ g, int ld,
                                             int row0, int k0, i8* lds, int tid) {
  constexpr int PER = (ROWS * 4) / NT;
#pragma unroll
  for (int q = 0; q < PER; ++q) {
    int s = q * NT + tid;
    int r = s >> 2;
    int kq = (s & 3) ^ ((r >> 1) & 3);
    async16(g + (size_t)(row0 + r) * ld + (k0 + kq * 16), lds + s * 16);
  }
}
__device__ __forceinline__ i32x4 frag_i8_k64(const i8* lds, int m, int q) {
  int phys = q ^ ((m >> 1) & 3);
  return *(const i32x4*)(lds + m * 64 + phys * 16);
}

// ---------- kernel 1: row L2-normalize X -> F (i8) ----------
__global__ __launch_bounds__(256) void k_normalize(const float* __restrict__ X,
                                                   i8* __restrict__ F) {
  int row = blockIdx.x;
  int tid = threadIdx.x;
  const float* xr = X + (size_t)row * DC;
  float2 v = *(const float2*)(xr + 2 * tid);
  float s = v.x * v.x + v.y * v.y;
#pragma unroll
  for (int off = 32; off; off >>= 1) s += __shfl_down(s, off);
  __shared__ float wsum[4];
  if ((tid & 63) == 0) wsum[tid >> 6] = s;
  __syncthreads();
  float tot = wsum[0] + wsum[1] + wsum[2] + wsum[3];
  float scale = QF_INV / fmaxf(sqrtf(tot), 1e-12f);
  int q0 = (int)rintf(v.x * scale);
  int q1 = (int)rintf(v.y * scale);
  q0 = q0 > 127 ? 127 : (q0 < -127 ? -127 : q0);
  q1 = q1 > 127 ? 127 : (q1 < -127 ? -127 : q1);
  u16 pk = (u16)((q0 & 255) | ((q1 & 255) << 8));
  ((u16*)(F + (size_t)row * DC))[tid] = pk;
}

// ---------- kernel 2: symmetric S = thr(F F^T), diag 0, i8 in / i8 out ----------
// 128x128 tiles, ti<=tj triangle (2080 blocks), 256 threads (4 waves 2x2).
// BK=64 -> 8 barrier pairs; TOTAL LDS 16 KB (As 8K + Bs 8K; epilogue reuses
// the same 16 KB as a single transpose buffer in two phases).
// rs: i32 sums, plain stores to rs_mat[64][2][8192] (per-wave slots, unique
// writer: col-sums [ti][wm][gj], row-sums [tj][wn][gi]; diag col-only).
__global__ __launch_bounds__(256, 4) void k_simgemm(const i8* __restrict__ F,
                                                    i8* __restrict__ S,
                                                    float* __restrict__ rs_mat) {
  __shared__ alignas(16) char smem[16384];
  i8* As = (i8*)smem;           // 128x64 i8 = 8 KB
  i8* Bs = (i8*)(smem + 8192);  // 128x64 i8 = 8 KB
  int tid = threadIdx.x, lane = tid & 63, wave = tid >> 6;
  // triangle decode: block -> (ti <= tj)
  int b = blockIdx.x;
  int tj = (int)((sqrtf(8.f * b + 1.f) - 1.f) * 0.5f);
  while ((tj + 1) * (tj + 2) / 2 <= b) ++tj;
  while (tj * (tj + 1) / 2 > b) --tj;
  int ti = b - tj * (tj + 1) / 2;
  bool diag = (ti == tj);

  int wm = wave >> 1, wn = wave & 1;
  int quad = lane >> 4, col = lane & 15;
  i32x4 zero = {0, 0, 0, 0};
  i32x4 acc[4][4];
#pragma unroll
  for (int a = 0; a < 4; ++a)
#pragma unroll
    for (int c = 0; c < 4; ++c) acc[a][c] = zero;

  const i8* Bsrc = diag ? As : Bs;
  for (int kt = 0; kt < DC; kt += 64) {  // 8 iterations
    __syncthreads();
    stage_i8_k64<128, 256>(F, DC, ti * 128, kt, As, tid);
    if (!diag) stage_i8_k64<128, 256>(F, DC, tj * 128, kt, Bs, tid);
    __syncthreads();
    i32x4 af[4], bfr[4];
#pragma unroll
    for (int mi = 0; mi < 4; ++mi)
      af[mi] = frag_i8_k64(As, wm * 64 + mi * 16 + col, quad);
#pragma unroll
    for (int ni = 0; ni < 4; ++ni)
      bfr[ni] = frag_i8_k64(Bsrc, wn * 64 + ni * 16 + col, quad);
#pragma unroll
    for (int mi = 0; mi < 4; ++mi)
#pragma unroll
      for (int ni = 0; ni < 4; ++ni)
        acc[mi][ni] = __builtin_amdgcn_mfma_i32_16x16x64_i8(af[mi], bfr[ni], acc[mi][ni], 0, 0, 0);
  }

  // integer threshold in place (max(acc,0) == thr(v,1e-10) exactly) + diag-0;
  // exact column/row sums in i32 (max 128*127*127*512 ~ 1.06e9 < 2^31)
  int csI[4] = {0, 0, 0, 0};
  int rvI[16];
#pragma unroll
  for (int u = 0; u < 16; ++u) rvI[u] = 0;
#pragma unroll
  for (int mi = 0; mi < 4; ++mi) {
#pragma unroll
    for (int r = 0; r < 4; ++r) {
      int gi = ti * 128 + wm * 64 + mi * 16 + quad * 4 + r;
#pragma unroll
      for (int ni = 0; ni < 4; ++ni) {
        int gj = tj * 128 + wn * 64 + ni * 16 + col;
        int a = acc[mi][ni][r];
        a = a > 0 ? a : 0;
        if (diag && gi == gj) a = 0;
        acc[mi][ni][r] = a;
        csI[ni] += a;
        rvI[mi * 4 + r] += a;
      }
    }
  }
  // per-wave column sums (64 rows each) -> slot rs_mat[ti][wm][gj]
#pragma unroll
  for (int ni = 0; ni < 4; ++ni) {
    int c = csI[ni];
    c += __shfl_xor(c, 16);
    c += __shfl_xor(c, 32);
    if (quad == 0) {
      int gj = tj * 128 + wn * 64 + ni * 16 + col;
      rs_mat[((size_t)ti * 2 + wm) * NR + gj] = (float)c * DEQA;
    }
  }
  // per-wave row sums (64 cols each) -> slot rs_mat[tj][wn][gi] (non-diag)
  if (!diag) {
#pragma unroll
    for (int u = 0; u < 16; ++u) {
      int c = rvI[u];
      c += __shfl_xor(c, 1);
      c += __shfl_xor(c, 2);
      c += __shfl_xor(c, 4);
      c += __shfl_xor(c, 8);
      if (col == 0) {
        int mi = u >> 2, r = u & 3;
        int gi = ti * 128 + wm * 64 + mi * 16 + quad * 4 + r;
        rs_mat[((size_t)tj * 2 + wn) * NR + gi] = (float)c * DEQA;
      }
    }
  }

  // ---- two-phase transpose epilogue in the single 16 KB buffer ----
  char* buf = smem;  // 128x128 i8 = 16 KB
  // phase A: direct tile
  __syncthreads();
#pragma unroll
  for (int mi = 0; mi < 4; ++mi) {
#pragma unroll
    for (int ni = 0; ni < 4; ++ni) {
      int cg = wn * 64 + ni * 16 + col;
#pragma unroll
      for (int r = 0; r < 4; ++r) {
        float avf = (float)acc[mi][ni][r] * DEQA;      // same numerics as R7
        int qq = (int)rintf(avf * QS_INV);
        qq = qq > 127 ? 127 : qq;                      // acc >= 0, no low clamp
        int row = wm * 64 + mi * 16 + quad * 4 + r;
        int chunk = (cg >> 4) ^ (row & 7);
        buf[row * 128 + chunk * 16 + (cg & 15)] = (char)qq;
      }
    }
  }
  __syncthreads();
  {
    int r2 = tid >> 1, half = tid & 1;
#pragma unroll
    for (int k = 0; k < 4; ++k) {
      int c = half * 4 + k;
      int phys = c ^ (r2 & 7);
      i32x4 d = *(const i32x4*)(buf + r2 * 128 + phys * 16);
      *(i32x4*)(S + (size_t)(ti * 128 + r2) * NR + tj * 128 + c * 16) = d;
    }
  }
  // phase B: mirror (transposed) tile
  if (!diag) {
    __syncthreads();
#pragma unroll
    for (int mi = 0; mi < 4; ++mi) {
#pragma unroll
      for (int ni = 0; ni < 4; ++ni) {
        int cg = wn * 64 + ni * 16 + col;
        int q[4];
#pragma unroll
        for (int r = 0; r < 4; ++r) {
          float avf = (float)acc[mi][ni][r] * DEQA;
          int qq = (int)rintf(avf * QS_INV);
          q[r] = qq > 127 ? 127 : qq;
        }
        int mcb = wm * 64 + mi * 16 + quad * 4;
        int chunk = (mcb >> 4) ^ (cg & 7);
        unsigned pk = (unsigned)(q[0] & 255) | ((unsigned)(q[1] & 255) << 8) |
                      ((unsigned)(q[2] & 255) << 16) | ((unsigned)(q[3] & 255) << 24);
        *(unsigned*)(buf + cg * 128 + chunk * 16 + (mcb & 15)) = pk;
      }
    }
    __syncthreads();
    {
      int r2 = tid >> 1, half = tid & 1;
#pragma unroll
      for (int k = 0; k < 4; ++k) {
        int c = half * 4 + k;
        int phys = c ^ (r2 & 7);
        i32x4 d = *(const i32x4*)(buf + r2 * 128 + phys * 16);
        *(i32x4*)(S + (size_t)(tj * 128 + r2) * NR + ti * 128 + c * 16) = d;
      }
    }
  }
}

// ---------- kernel 2b: rsum1[i] = 1 + sum_k rs_mat[k][i] (128 partials) ----------
__global__ __launch_bounds__(128) void k_rs(const float* __restrict__ rs_mat,
                                            float* __restrict__ rsum1) {
  int i = blockIdx.x * 128 + threadIdx.x;
  float s = 1.0f;
#pragma unroll
  for (int k = 0; k < 128; ++k) s += rs_mat[(size_t)k * NR + i];
  rsum1[i] = s;
}

// ---------- kernel 3: Yt[n][j] = i8(dinv_j * X[j][n] / sY); dinv from rsum1 ----------
__global__ __launch_bounds__(256) void k_make_yt(const float* __restrict__ X,
                                                 const float* __restrict__ rsum1,
                                                 i8* __restrict__ Yt) {
  __shared__ float T[64][65];
  int i0 = blockIdx.x * 64, k0 = blockIdx.y * 64;
  int tid = threadIdx.x;
  {
    int iL = tid >> 2, ks = (tid & 3) * 4;
    const float* xr = X + (size_t)(i0 + iL) * DC + k0;
#pragma unroll
    for (int u = 0; u < 4; ++u) {
      float4 f = *(const float4*)(xr + ks + u * 16);
      T[iL][ks + u * 16 + 0] = f.x;
      T[iL][ks + u * 16 + 1] = f.y;
      T[iL][ks + u * 16 + 2] = f.z;
      T[iL][ks + u * 16 + 3] = f.w;
    }
  }
  __syncthreads();
  {
    int kL = tid >> 2, ib = (tid & 3) * 16;
    char pk[16];
#pragma unroll
    for (int u = 0; u < 16; ++u) {
      float dj = rsqrtf(rsum1[i0 + ib + u]);
      float v = T[ib + u][kL] * dj;
      int q = (int)rintf(v * QY_INV);
      q = q > 127 ? 127 : (q < -127 ? -127 : q);
      pk[u] = (char)q;
    }
    *(i32x4*)(Yt + (size_t)(k0 + kL) * NR + i0 + ib) = *(const i32x4*)pk;
  }
}

// ---------- kernel 4: split-K i8 GEMM partials = S @ Yt^T (R7-proven form) ----------
// 512 threads, block tile 128x256, BK=128 (16 iters), per-wave 64x64.
__global__ __launch_bounds__(512, 4) void k_outgemm(const i8* __restrict__ S,
                                                    const i8* __restrict__ Yt,
                                                    u16* __restrict__ Pb) {
  __shared__ alignas(16) i8 As[128 * 128];  // 16 KB
  __shared__ alignas(16) i8 Bs[256 * 128];  // 32 KB
  int tid = threadIdx.x, lane = tid & 63, wave = tid >> 6;
  int tn = blockIdx.x, ti = blockIdx.y, kz = blockIdx.z;
  int wm = wave & 1, wn = wave >> 1;  // 2 x 4 wave grid
  int quad = lane >> 4, col = lane & 15;
  i32x4 zero = {0, 0, 0, 0};
  i32x4 acc[4][4];
#pragma unroll
  for (int a = 0; a < 4; ++a)
#pragma unroll
    for (int c = 0; c < 4; ++c) acc[a][c] = zero;

  const int KCH = NR / KZN;
  int k_lo = kz * KCH, k_hi = k_lo + KCH;
  for (int kt = k_lo; kt < k_hi; kt += 128) {
    __syncthreads();
    stage_i8_k128<128, 512>(S, NR, ti * 128, kt, As, tid);
    stage_i8_k128<256, 512>(Yt, NR, tn * 256, kt, Bs, tid);
    __syncthreads();
#pragma unroll
    for (int kc = 0; kc < 2; ++kc) {
      i32x4 af[4], bfr[4];
#pragma unroll
      for (int mi = 0; mi < 4; ++mi)
        af[mi] = frag_i8_k128(As, wm * 64 + mi * 16 + col, kc * 4 + quad);
#pragma unroll
      for (int ni = 0; ni < 4; ++ni)
        bfr[ni] = frag_i8_k128(Bs, wn * 64 + ni * 16 + col, kc * 4 + quad);
#pragma unroll
      for (int mi = 0; mi < 4; ++mi)
#pragma unroll
        for (int ni = 0; ni < 4; ++ni)
          acc[mi][ni] = __builtin_amdgcn_mfma_i32_16x16x64_i8(af[mi], bfr[ni], acc[mi][ni], 0, 0, 0);
    }
  }
#pragma unroll
  for (int mi = 0; mi < 4; ++mi) {
#pragma unroll
    for (int r = 0; r < 4; ++r) {
      int gi = ti * 128 + wm * 64 + mi * 16 + quad * 4 + r;
#pragma unroll
      for (int ni = 0; ni < 4; ++ni) {
        int gj = tn * 256 + wn * 64 + ni * 16 + col;
        Pb[((size_t)kz * NR + gi) * DC + gj] = f2bf((float)acc[mi][ni][r] * DEQ);
      }
    }
  }
}

// ---------- kernel 5: reduce partials + xs*X -> out ----------
__global__ __launch_bounds__(256) void k_reduce(const u16* __restrict__ Pb,
                                               const float* __restrict__ X,
                                               const float* __restrict__ rsum1,
                                               float* __restrict__ out) {
  const float c1 = (float)(2.0 / 3.0);
  const float c0 = 1.0f - c1;
  size_t idx = ((size_t)blockIdx.x * 256 + threadIdx.x) * 4;
  int i = (int)(idx >> 9);  // row = idx / DC
  float4 s = {0.f, 0.f, 0.f, 0.f};
#pragma unroll
  for (int kz = 0; kz < KZN; ++kz) {
    u16x4 p = *(const u16x4*)(Pb + (size_t)kz * NR * DC + idx);
    s.x += bf2f(p[0]); s.y += bf2f(p[1]); s.z += bf2f(p[2]); s.w += bf2f(p[3]);
  }
  float4 x = *(const float4*)(X + idx);
  float rs = rsum1[i];
  float sc = c1 * rsqrtf(rs);
  float xs = c0 + c1 / rs;
  float4 o = {xs * x.x + sc * s.x, xs * x.y + sc * s.y,
              xs * x.z + sc * s.z, xs * x.w + sc * s.w};
  *(float4*)(out + idx) = o;
}

extern "C" void kernel_launch(void* const* d_in, const int* in_sizes, int n_in,
                              void* d_out, int out_size, void* d_ws, size_t ws_size,
                              hipStream_t stream) {
  const float* X = (const float*)d_in[0];
  float* out = (float*)d_out;
  char* ws = (char*)d_ws;
  // ws layout — total 109,084,672 B, byte-identical footprint to proven R7.
  // rs_mat (4 MB) ALIASES the start of Pb: fully consumed by k_rs before
  // k_outgemm writes Pb (same stream -> serialized). No overlap live.
  i8*  S  = (i8*)(ws);                         // 67108864
  i8*  F  = (i8*)(ws + 67108864);              //  4194304
  i8*  Yt = (i8*)(ws + 71303168);              //  4194304
  float* rsum1  = (float*)(ws + 75497472);     //    32768
  u16* Pb = (u16*)(ws + 75530240);             // KZN*8192*512*2 = 33554432
  float* rs_mat = (float*)(ws + 75530240);     // 64*2*8192*4 = 4194304 (alias)

  k_normalize<<<dim3(NR), dim3(256), 0, stream>>>(X, F);
  k_simgemm<<<dim3(64 * 65 / 2), dim3(256), 0, stream>>>(F, S, rs_mat);
  k_rs<<<dim3(64), dim3(128), 0, stream>>>(rs_mat, rsum1);
  k_make_yt<<<dim3(128, 8), dim3(256), 0, stream>>>(X, rsum1, Yt);
  k_outgemm<<<dim3(2, 64, KZN), dim3(512), 0, stream>>>(S, Yt, Pb);
  k_reduce<<<dim3(NR * DC / 1024), dim3(256), 0, stream>>>(Pb, X, rsum1, out);
}